// Round 2
// baseline (157.211 us; speedup 1.0000x reference)
//
#include <hip/hip_runtime.h>
#include <hip/hip_cooperative_groups.h>

namespace cg = cooperative_groups;

// Problem constants (from reference)
#define NRB 512
#define NTK 1024
#define DD  64
#define GHH 128

// Dead dataflow note: tgt = edge_index[1] + 512 ∈ [512,1536) but robot_msgs =
// agg[:512] -> all-zero. Entire edge MLP + segment_sum is dead; output depends
// only on x_robot, x_task, Wv*, Wm*.  lrelu(x) = 0.55x + 0.45|x| (slope 0.1)
// factors the score into a[n] + c[m] + sum_h wb[h]*|HR[n,h]+HTB[m,h]|.

// Workspace layout (floats):
//   HR  [512][128]  @ 0
//   HTB [1024][128] @ 65536
//   a   [512]       @ 196608
//   c   [1024]      @ 197120
//   wb  [128]       @ 198144

// ---------------------------------------------------------------------------
// Single cooperative kernel: phase P (prep) -> grid.sync -> phase S (scores)
// -> grid.sync -> phase X (row softmax). 256 blocks x 256 threads = 1 block/CU.
// ---------------------------------------------------------------------------
__global__ __launch_bounds__(256) void fused_kernel(
    const float* __restrict__ xr, const float* __restrict__ xt,
    const float* __restrict__ Wv1, const float* __restrict__ bv1,
    const float* __restrict__ Wv2, const float* __restrict__ bv2,
    const float* __restrict__ Wm1, const float* __restrict__ bm1,
    const float* __restrict__ Wm2, const float* __restrict__ bm2,
    float* __restrict__ HR, float* __restrict__ HTB,
    float* __restrict__ av, float* __restrict__ cv, float* __restrict__ wbv,
    float* __restrict__ out)
{
    cg::grid_group grid = cg::this_grid();
    const int b    = blockIdx.x;
    const int tid  = threadIdx.x;
    const int half = tid >> 7;     // two independent 128-thread halves
    const int i    = tid & 127;

    __shared__ float xs[2][4][DD];
    __shared__ float sA[2][4][GHH];
    __shared__ float sB[2][4][GHH];
    __shared__ float sR[2][4][GHH];

    // =================== Phase P: prep ===================
    if (b < 64) {
        // -------- robot path: 3-layer MLP -> HR row + a[n] --------
        const int r0 = (b * 2 + half) * 4;
        float* xsh = &xs[half][0][0];
        xsh[i]       = xr[r0 * DD + i];
        xsh[128 + i] = xr[r0 * DD + 128 + i];
        __syncthreads();

        // h1[r][i] = lrelu(bv1[i] + x[r] . Wv1[i,128:192])
        {
            float4 w[16];
            const float4* wp = reinterpret_cast<const float4*>(Wv1 + i * 192 + 128);
            #pragma unroll
            for (int q = 0; q < 16; ++q) w[q] = wp[q];
            const float bb = bv1[i];
            for (int r = 0; r < 4; ++r) {
                float acc = bb;
                #pragma unroll
                for (int q = 0; q < 16; ++q) {
                    acc = fmaf(w[q].x, xs[half][r][q*4+0], acc);
                    acc = fmaf(w[q].y, xs[half][r][q*4+1], acc);
                    acc = fmaf(w[q].z, xs[half][r][q*4+2], acc);
                    acc = fmaf(w[q].w, xs[half][r][q*4+3], acc);
                }
                sA[half][r][i] = (acc >= 0.f) ? acc : 0.1f * acc;
            }
        }
        __syncthreads();

        // h[r][i] = bv2[i] + h1[r] . Wv2[i,:]
        {
            float4 w[32];
            const float4* wp = reinterpret_cast<const float4*>(Wv2 + i * GHH);
            #pragma unroll
            for (int q = 0; q < 32; ++q) w[q] = wp[q];
            const float bb = bv2[i];
            for (int r = 0; r < 4; ++r) {
                float acc = bb;
                const float4* hp = reinterpret_cast<const float4*>(sA[half][r]);
                #pragma unroll
                for (int q = 0; q < 32; ++q) {
                    float4 h4 = hp[q];
                    acc = fmaf(w[q].x, h4.x, acc);
                    acc = fmaf(w[q].y, h4.y, acc);
                    acc = fmaf(w[q].z, h4.z, acc);
                    acc = fmaf(w[q].w, h4.w, acc);
                }
                sB[half][r][i] = acc;
            }
        }
        __syncthreads();

        // hr[r][i] = h[r] . Wm1[i,:128]; partial for a[n]
        {
            float4 w[32];
            const float4* wp = reinterpret_cast<const float4*>(Wm1 + i * 192);
            #pragma unroll
            for (int q = 0; q < 32; ++q) w[q] = wp[q];
            const float wm2 = Wm2[i];
            for (int r = 0; r < 4; ++r) {
                float acc = 0.f;
                const float4* hp = reinterpret_cast<const float4*>(sB[half][r]);
                #pragma unroll
                for (int q = 0; q < 32; ++q) {
                    float4 h4 = hp[q];
                    acc = fmaf(w[q].x, h4.x, acc);
                    acc = fmaf(w[q].y, h4.y, acc);
                    acc = fmaf(w[q].z, h4.z, acc);
                    acc = fmaf(w[q].w, h4.w, acc);
                }
                HR[(r0 + r) * GHH + i] = acc;
                sR[half][r][i] = wm2 * acc;
            }
        }
        __syncthreads();
        {
            const int r = i >> 5, c = i & 31;
            float s = sR[half][r][c] + sR[half][r][c+32]
                    + sR[half][r][c+64] + sR[half][r][c+96];
            #pragma unroll
            for (int off = 16; off >= 1; off >>= 1) s += __shfl_xor(s, off, 32);
            if (c == 0) av[r0 + r] = 0.55f * s;
        }
    } else if (b < 192) {
        // -------- task path: HTB = x_task@Wm1[:,128:].T + bm1, c[m] --------
        const int t0 = ((b - 64) * 2 + half) * 4;
        float* xsh = &xs[half][0][0];
        xsh[i]       = xt[t0 * DD + i];
        xsh[128 + i] = xt[t0 * DD + 128 + i];
        __syncthreads();

        float4 w[16];
        const float4* wp = reinterpret_cast<const float4*>(Wm1 + i * 192 + 128);
        #pragma unroll
        for (int q = 0; q < 16; ++q) w[q] = wp[q];
        const float bb  = bm1[i];
        const float wm2 = Wm2[i];
        for (int t = 0; t < 4; ++t) {
            float acc = bb;
            #pragma unroll
            for (int q = 0; q < 16; ++q) {
                acc = fmaf(w[q].x, xs[half][t][q*4+0], acc);
                acc = fmaf(w[q].y, xs[half][t][q*4+1], acc);
                acc = fmaf(w[q].z, xs[half][t][q*4+2], acc);
                acc = fmaf(w[q].w, xs[half][t][q*4+3], acc);
            }
            HTB[(t0 + t) * GHH + i] = acc;   // includes bm1
            sR[half][t][i] = wm2 * acc;
        }
        __syncthreads();
        {
            const int r = i >> 5, c = i & 31;
            float s = sR[half][r][c] + sR[half][r][c+32]
                    + sR[half][r][c+64] + sR[half][r][c+96];
            #pragma unroll
            for (int off = 16; off >= 1; off >>= 1) s += __shfl_xor(s, off, 32);
            if (c == 0) cv[t0 + r] = 0.55f * s + bm2[0];
        }
    } else if (b == 192 && tid < GHH) {
        wbv[tid] = 0.45f * Wm2[tid];
    }

    __threadfence();
    grid.sync();

    // =================== Phase S: scores ===================
    // scores[n][m] = sum_h wb[h]*|HR[n,h]+HTB[m,h]| + a[n] + c[m]
    {
        const int mc = b & 3;
        const int ng = b >> 2;
        const int m  = mc * 256 + tid;
        const int n0 = ng * 8;

        float accA[8], accB[8];
        #pragma unroll
        for (int k = 0; k < 8; ++k) { accA[k] = 0.f; accB[k] = 0.f; }

        const float4* htbp = reinterpret_cast<const float4*>(HTB + m * GHH);

        for (int hc = 0; hc < 4; ++hc) {
            float4 hb[8];
            #pragma unroll
            for (int q = 0; q < 8; ++q) hb[q] = htbp[hc * 8 + q];
            float4 wr[8];
            const float4* wp = reinterpret_cast<const float4*>(wbv + hc * 32);
            #pragma unroll
            for (int q = 0; q < 8; ++q) wr[q] = wp[q];

            #pragma unroll
            for (int nn = 0; nn < 8; ++nn) {
                const float4* hrp =
                    reinterpret_cast<const float4*>(HR + (n0 + nn) * GHH + hc * 32);
                float a0 = 0.f, a1 = 0.f;
                #pragma unroll
                for (int q = 0; q < 8; ++q) {
                    float4 h4 = hrp[q];
                    float x0 = h4.x + hb[q].x;
                    float x1 = h4.y + hb[q].y;
                    float x2 = h4.z + hb[q].z;
                    float x3 = h4.w + hb[q].w;
                    a0 = fmaf(wr[q].x, fabsf(x0), a0);
                    a1 = fmaf(wr[q].y, fabsf(x1), a1);
                    a0 = fmaf(wr[q].z, fabsf(x2), a0);
                    a1 = fmaf(wr[q].w, fabsf(x3), a1);
                }
                accA[nn] += a0; accB[nn] += a1;
            }
        }

        const float cm = cv[m];
        #pragma unroll
        for (int nn = 0; nn < 8; ++nn)
            out[(n0 + nn) * NTK + m] = accA[nn] + accB[nn] + av[n0 + nn] + cm;
    }

    __threadfence();
    grid.sync();

    // =================== Phase X: row softmax (2 rows/block) ===================
    {
        __shared__ float sm[4], ss[4];
        const int wid = tid >> 6, lane = tid & 63;
        for (int rr = 0; rr < 2; ++rr) {
            float* row = out + (b * 2 + rr) * NTK;
            float v0 = row[tid], v1 = row[tid + 256];
            float v2 = row[tid + 512], v3 = row[tid + 768];
            float mx = fmaxf(fmaxf(v0, v1), fmaxf(v2, v3));
            #pragma unroll
            for (int off = 32; off >= 1; off >>= 1)
                mx = fmaxf(mx, __shfl_xor(mx, off, 64));
            if (lane == 0) sm[wid] = mx;
            __syncthreads();
            mx = fmaxf(fmaxf(sm[0], sm[1]), fmaxf(sm[2], sm[3]));

            float e0 = expf(v0 - mx), e1 = expf(v1 - mx);
            float e2 = expf(v2 - mx), e3 = expf(v3 - mx);
            float s = e0 + e1 + e2 + e3;
            #pragma unroll
            for (int off = 32; off >= 1; off >>= 1) s += __shfl_xor(s, off, 64);
            if (lane == 0) ss[wid] = s;
            __syncthreads();
            s = ss[0] + ss[1] + ss[2] + ss[3];

            const float inv = 1.0f / s;
            row[tid]       = e0 * inv;
            row[tid + 256] = e1 * inv;
            row[tid + 512] = e2 * inv;
            row[tid + 768] = e3 * inv;
            __syncthreads();
        }
    }
}

extern "C" void kernel_launch(void* const* d_in, const int* in_sizes, int n_in,
                              void* d_out, int out_size, void* d_ws, size_t ws_size,
                              hipStream_t stream)
{
    const float* xr  = (const float*)d_in[0];
    const float* xt  = (const float*)d_in[1];
    // d_in[2]=edge_index, [3]=edge_attr, [4..7]=We1,be1,We2,be2 : provably dead
    const float* Wv1 = (const float*)d_in[8];
    const float* bv1 = (const float*)d_in[9];
    const float* Wv2 = (const float*)d_in[10];
    const float* bv2 = (const float*)d_in[11];
    const float* Wm1 = (const float*)d_in[12];
    const float* bm1 = (const float*)d_in[13];
    const float* Wm2 = (const float*)d_in[14];
    const float* bm2 = (const float*)d_in[15];

    float* ws  = (float*)d_ws;
    float* HR  = ws;
    float* HTB = ws + 65536;
    float* av  = ws + 196608;
    float* cv  = ws + 197120;
    float* wbv = ws + 198144;
    float* out = (float*)d_out;

    void* args[] = { (void*)&xr, (void*)&xt,
                     (void*)&Wv1, (void*)&bv1, (void*)&Wv2, (void*)&bv2,
                     (void*)&Wm1, (void*)&bm1, (void*)&Wm2, (void*)&bm2,
                     (void*)&HR, (void*)&HTB, (void*)&av, (void*)&cv,
                     (void*)&wbv, (void*)&out };

    hipLaunchCooperativeKernel((const void*)fused_kernel,
                               dim3(256), dim3(256), args, 0, stream);
}

// Round 3
// 43.166 us; speedup vs baseline: 3.6420x; 3.6420x over previous
//
#include <hip/hip_runtime.h>

// Problem constants (from reference)
#define NRB 512
#define NTK 1024
#define DD  64
#define GHH 128

// Dead dataflow note: tgt = edge_index[1] + 512 in [512,1536) but robot_msgs =
// agg[:512] -> all-zero. Entire edge MLP + segment_sum is dead; output depends
// only on x_robot, x_task, Wv*, Wm*.  lrelu(x) = 0.55x + 0.45|x| (slope 0.1)
// factors the score into a[n] + c[m] + sum_h wb[h]*|HR[n,h]+HTB[m,h]|.
//
// Round-2 lesson: cooperative grid.sync costs ~60us/sync on MI355X (cross-XCD
// fence + 256-block spin). Kernel-boundary handoff is far cheaper. -> 2 plain
// kernels: prep, then score+softmax fused (block owns whole rows).

// Workspace layout (floats):
//   HR  [512][128]  @ 0
//   HTB [1024][128] @ 65536
//   a   [512]       @ 196608
//   c   [1024]      @ 197120
//   wb  [128]       @ 198144

// ---------------------------------------------------------------------------
// Kernel A: prep. Robot blocks (0..127): 4 robots each, 3-layer MLP ->
// HR[n][h] and a[n]. Task blocks (128..383): 4 tasks each ->
// HTB[m][h] = x_task@Wm1[:,128:].T + bm1 and c[m].
// ---------------------------------------------------------------------------
__global__ __launch_bounds__(128) void prep_kernel(
    const float* __restrict__ xr, const float* __restrict__ xt,
    const float* __restrict__ Wv1, const float* __restrict__ bv1,
    const float* __restrict__ Wv2, const float* __restrict__ bv2,
    const float* __restrict__ Wm1, const float* __restrict__ bm1,
    const float* __restrict__ Wm2, const float* __restrict__ bm2,
    float* __restrict__ HR, float* __restrict__ HTB,
    float* __restrict__ av, float* __restrict__ cv, float* __restrict__ wbv)
{
    const int i = threadIdx.x;      // 0..127
    __shared__ float xs[4][DD];     // 4 input rows
    __shared__ float sA[4][GHH];    // h1
    __shared__ float sB[4][GHH];    // h
    __shared__ float sR[4][GHH];    // reduction scratch

    if (blockIdx.x < NRB / 4) {
        // -------- robot path --------
        const int r0 = blockIdx.x * 4;
        ((float*)xs)[i]       = xr[r0 * DD + i];
        ((float*)xs)[128 + i] = xr[r0 * DD + 128 + i];
        __syncthreads();

        // phase 1: h1[r][i] = lrelu(bv1[i] + x[r] . Wv1[i, 128:192])
        {
            float4 w[16];
            const float4* wp = reinterpret_cast<const float4*>(Wv1 + i * 192 + 128);
            #pragma unroll
            for (int q = 0; q < 16; ++q) w[q] = wp[q];
            const float b = bv1[i];
            for (int r = 0; r < 4; ++r) {
                float acc = b;
                #pragma unroll
                for (int q = 0; q < 16; ++q) {
                    acc = fmaf(w[q].x, xs[r][q*4+0], acc);
                    acc = fmaf(w[q].y, xs[r][q*4+1], acc);
                    acc = fmaf(w[q].z, xs[r][q*4+2], acc);
                    acc = fmaf(w[q].w, xs[r][q*4+3], acc);
                }
                sA[r][i] = (acc >= 0.f) ? acc : 0.1f * acc;
            }
        }
        __syncthreads();

        // phase 2: h[r][i] = bv2[i] + h1[r] . Wv2[i, :]
        {
            float4 w[32];
            const float4* wp = reinterpret_cast<const float4*>(Wv2 + i * GHH);
            #pragma unroll
            for (int q = 0; q < 32; ++q) w[q] = wp[q];
            const float b = bv2[i];
            for (int r = 0; r < 4; ++r) {
                float acc = b;
                const float4* hp = reinterpret_cast<const float4*>(sA[r]);
                #pragma unroll
                for (int q = 0; q < 32; ++q) {
                    float4 h4 = hp[q];
                    acc = fmaf(w[q].x, h4.x, acc);
                    acc = fmaf(w[q].y, h4.y, acc);
                    acc = fmaf(w[q].z, h4.z, acc);
                    acc = fmaf(w[q].w, h4.w, acc);
                }
                sB[r][i] = acc;   // no activation on h
            }
        }
        __syncthreads();

        // phase 3: hr[r][i] = h[r] . Wm1[i, :128];  a[n] = 0.55 * sum w*hr
        {
            float4 w[32];
            const float4* wp = reinterpret_cast<const float4*>(Wm1 + i * 192);
            #pragma unroll
            for (int q = 0; q < 32; ++q) w[q] = wp[q];
            const float wm2 = Wm2[i];
            for (int r = 0; r < 4; ++r) {
                float acc = 0.f;
                const float4* hp = reinterpret_cast<const float4*>(sB[r]);
                #pragma unroll
                for (int q = 0; q < 32; ++q) {
                    float4 h4 = hp[q];
                    acc = fmaf(w[q].x, h4.x, acc);
                    acc = fmaf(w[q].y, h4.y, acc);
                    acc = fmaf(w[q].z, h4.z, acc);
                    acc = fmaf(w[q].w, h4.w, acc);
                }
                HR[(r0 + r) * GHH + i] = acc;
                sR[r][i] = wm2 * acc;
            }
        }
        __syncthreads();
        {
            const int r = i >> 5, c = i & 31;
            float s = sR[r][c] + sR[r][c+32] + sR[r][c+64] + sR[r][c+96];
            #pragma unroll
            for (int off = 16; off >= 1; off >>= 1) s += __shfl_xor(s, off, 32);
            if (c == 0) av[r0 + r] = 0.55f * s;
        }
    } else {
        // -------- task path --------
        const int t0 = (blockIdx.x - NRB / 4) * 4;
        ((float*)xs)[i]       = xt[t0 * DD + i];
        ((float*)xs)[128 + i] = xt[t0 * DD + 128 + i];
        __syncthreads();

        float4 w[16];
        const float4* wp = reinterpret_cast<const float4*>(Wm1 + i * 192 + 128);
        #pragma unroll
        for (int q = 0; q < 16; ++q) w[q] = wp[q];
        const float b   = bm1[i];
        const float wm2 = Wm2[i];
        for (int t = 0; t < 4; ++t) {
            float acc = b;
            #pragma unroll
            for (int q = 0; q < 16; ++q) {
                acc = fmaf(w[q].x, xs[t][q*4+0], acc);
                acc = fmaf(w[q].y, xs[t][q*4+1], acc);
                acc = fmaf(w[q].z, xs[t][q*4+2], acc);
                acc = fmaf(w[q].w, xs[t][q*4+3], acc);
            }
            HTB[(t0 + t) * GHH + i] = acc;   // includes bm1
            sR[t][i] = wm2 * acc;
        }
        __syncthreads();
        {
            const int r = i >> 5, c = i & 31;
            float s = sR[r][c] + sR[r][c+32] + sR[r][c+64] + sR[r][c+96];
            #pragma unroll
            for (int off = 16; off >= 1; off >>= 1) s += __shfl_xor(s, off, 32);
            if (c == 0) cv[t0 + r] = 0.55f * s + bm2[0];
        }
        if (blockIdx.x == NRB / 4 && i < GHH) wbv[i] = 0.45f * wm2;
    }
}

// ---------------------------------------------------------------------------
// Kernel B: fused score + softmax. 256 blocks x 256 threads; block b owns
// rows n0 = 2b, 2b+1 (all 1024 m). Thread owns m = msub*256+tid for msub
// 0..3. scores = sum_h wb[h]*|HR[n,h]+HTB[m,h]| + a[n] + c[m], then
// block-local softmax over the 1024 columns, single coalesced write.
// ---------------------------------------------------------------------------
__global__ __launch_bounds__(256) void score_softmax_kernel(
    const float* __restrict__ HR, const float* __restrict__ HTB,
    const float* __restrict__ av, const float* __restrict__ cv,
    const float* __restrict__ wbv, float* __restrict__ out)
{
    const int b   = blockIdx.x;
    const int tid = threadIdx.x;
    const int n0  = b * 2;

    float accA[2][4], accB[2][4];
    #pragma unroll
    for (int n = 0; n < 2; ++n)
        #pragma unroll
        for (int k = 0; k < 4; ++k) { accA[n][k] = 0.f; accB[n][k] = 0.f; }

    #pragma unroll
    for (int msub = 0; msub < 4; ++msub) {
        const int m = msub * 256 + tid;
        const float4* htbp = reinterpret_cast<const float4*>(HTB + m * GHH);

        for (int hc = 0; hc < 4; ++hc) {
            float4 hb[8];
            #pragma unroll
            for (int q = 0; q < 8; ++q) hb[q] = htbp[hc * 8 + q];
            float4 wr[8];
            const float4* wp = reinterpret_cast<const float4*>(wbv + hc * 32);
            #pragma unroll
            for (int q = 0; q < 8; ++q) wr[q] = wp[q];

            #pragma unroll
            for (int n = 0; n < 2; ++n) {
                const float4* hrp =
                    reinterpret_cast<const float4*>(HR + (n0 + n) * GHH + hc * 32);
                float a0 = 0.f, a1 = 0.f;
                #pragma unroll
                for (int q = 0; q < 8; ++q) {
                    float4 h4 = hrp[q];
                    float x0 = h4.x + hb[q].x;
                    float x1 = h4.y + hb[q].y;
                    float x2 = h4.z + hb[q].z;
                    float x3 = h4.w + hb[q].w;
                    a0 = fmaf(wr[q].x, fabsf(x0), a0);
                    a1 = fmaf(wr[q].y, fabsf(x1), a1);
                    a0 = fmaf(wr[q].z, fabsf(x2), a0);
                    a1 = fmaf(wr[q].w, fabsf(x3), a1);
                }
                accA[n][msub] += a0; accB[n][msub] += a1;
            }
        }
    }

    // finalize scores: + a[n] + c[m]
    float sc[2][4];
    #pragma unroll
    for (int msub = 0; msub < 4; ++msub) {
        const float cm = cv[msub * 256 + tid];
        #pragma unroll
        for (int n = 0; n < 2; ++n)
            sc[n][msub] = accA[n][msub] + accB[n][msub] + av[n0 + n] + cm;
    }

    // block-local softmax over 1024 columns for each of the 2 rows
    __shared__ float sm[2][4], ss[2][4];
    const int wid = tid >> 6, lane = tid & 63;

    float mx[2];
    #pragma unroll
    for (int n = 0; n < 2; ++n) {
        float m0 = fmaxf(fmaxf(sc[n][0], sc[n][1]), fmaxf(sc[n][2], sc[n][3]));
        #pragma unroll
        for (int off = 32; off >= 1; off >>= 1)
            m0 = fmaxf(m0, __shfl_xor(m0, off, 64));
        if (lane == 0) sm[n][wid] = m0;
        mx[n] = m0;
    }
    __syncthreads();
    #pragma unroll
    for (int n = 0; n < 2; ++n)
        mx[n] = fmaxf(fmaxf(sm[n][0], sm[n][1]), fmaxf(sm[n][2], sm[n][3]));

    float ex[2][4], sum[2];
    #pragma unroll
    for (int n = 0; n < 2; ++n) {
        float s = 0.f;
        #pragma unroll
        for (int msub = 0; msub < 4; ++msub) {
            ex[n][msub] = expf(sc[n][msub] - mx[n]);
            s += ex[n][msub];
        }
        #pragma unroll
        for (int off = 32; off >= 1; off >>= 1) s += __shfl_xor(s, off, 64);
        if (lane == 0) ss[n][wid] = s;
        sum[n] = s;
    }
    __syncthreads();
    #pragma unroll
    for (int n = 0; n < 2; ++n) {
        sum[n] = ss[n][0] + ss[n][1] + ss[n][2] + ss[n][3];
        const float inv = 1.0f / sum[n];
        #pragma unroll
        for (int msub = 0; msub < 4; ++msub)
            out[(n0 + n) * NTK + msub * 256 + tid] = ex[n][msub] * inv;
    }
}

extern "C" void kernel_launch(void* const* d_in, const int* in_sizes, int n_in,
                              void* d_out, int out_size, void* d_ws, size_t ws_size,
                              hipStream_t stream)
{
    const float* xr  = (const float*)d_in[0];
    const float* xt  = (const float*)d_in[1];
    // d_in[2]=edge_index, [3]=edge_attr, [4..7]=We1,be1,We2,be2 : provably dead
    const float* Wv1 = (const float*)d_in[8];
    const float* bv1 = (const float*)d_in[9];
    const float* Wv2 = (const float*)d_in[10];
    const float* bv2 = (const float*)d_in[11];
    const float* Wm1 = (const float*)d_in[12];
    const float* bm1 = (const float*)d_in[13];
    const float* Wm2 = (const float*)d_in[14];
    const float* bm2 = (const float*)d_in[15];

    float* ws  = (float*)d_ws;
    float* HR  = ws;
    float* HTB = ws + 65536;
    float* av  = ws + 196608;
    float* cv  = ws + 197120;
    float* wbv = ws + 198144;
    float* out = (float*)d_out;

    hipLaunchKernelGGL(prep_kernel, dim3(384), dim3(128), 0, stream,
                       xr, xt, Wv1, bv1, Wv2, bv2, Wm1, bm1, Wm2, bm2,
                       HR, HTB, av, cv, wbv);
    hipLaunchKernelGGL(score_softmax_kernel, dim3(256), dim3(256), 0, stream,
                       HR, HTB, av, cv, wbv, out);
}

// Round 4
// 32.695 us; speedup vs baseline: 4.8085x; 1.3203x over previous
//
#include <hip/hip_runtime.h>

// Problem constants (from reference)
#define NRB 512
#define NTK 1024
#define DD  64
#define GHH 128

// Dead dataflow note: tgt = edge_index[1] + 512 in [512,1536) but robot_msgs =
// agg[:512] -> all-zero. Entire edge MLP + segment_sum is dead; output depends
// only on x_robot, x_task, Wv*, Wm*.  lrelu(x) = 0.55x + 0.45|x| (slope 0.1)
// factors the score into a[n] + c[m] + sum_h wb[h]*|HR[n,h]+HTB[m,h]|.
//
// Round-2 lesson: cooperative grid.sync ~60us/sync on MI355X. Use kernel
// boundaries.
// Round-3 lesson: Tn=2 with 4 m's/thread -> 256 VGPR, 2 waves/SIMD,
// latency-bound (VALUBusy 8%). Fix: 1024-thread blocks (4 waves/SIMD TLP),
// one m per thread (reuse htb chunk across both n rows), launch_bounds caps
// VGPR at 128.

// Workspace layout (floats):
//   HR  [512][128]  @ 0
//   HTB [1024][128] @ 65536
//   a   [512]       @ 196608
//   c   [1024]      @ 197120
//   wb  [128]       @ 198144

// ---------------------------------------------------------------------------
// Kernel A: prep. Robot blocks (0..127): 4 robots each, 3-layer MLP ->
// HR[n][h] and a[n]. Task blocks (128..383): 4 tasks each ->
// HTB[m][h] = x_task@Wm1[:,128:].T + bm1 and c[m].
// ---------------------------------------------------------------------------
__global__ __launch_bounds__(128) void prep_kernel(
    const float* __restrict__ xr, const float* __restrict__ xt,
    const float* __restrict__ Wv1, const float* __restrict__ bv1,
    const float* __restrict__ Wv2, const float* __restrict__ bv2,
    const float* __restrict__ Wm1, const float* __restrict__ bm1,
    const float* __restrict__ Wm2, const float* __restrict__ bm2,
    float* __restrict__ HR, float* __restrict__ HTB,
    float* __restrict__ av, float* __restrict__ cv, float* __restrict__ wbv)
{
    const int i = threadIdx.x;      // 0..127
    __shared__ float xs[4][DD];     // 4 input rows
    __shared__ float sA[4][GHH];    // h1
    __shared__ float sB[4][GHH];    // h
    __shared__ float sR[4][GHH];    // reduction scratch

    if (blockIdx.x < NRB / 4) {
        // -------- robot path --------
        const int r0 = blockIdx.x * 4;
        ((float*)xs)[i]       = xr[r0 * DD + i];
        ((float*)xs)[128 + i] = xr[r0 * DD + 128 + i];
        __syncthreads();

        // phase 1: h1[r][i] = lrelu(bv1[i] + x[r] . Wv1[i, 128:192])
        {
            float4 w[16];
            const float4* wp = reinterpret_cast<const float4*>(Wv1 + i * 192 + 128);
            #pragma unroll
            for (int q = 0; q < 16; ++q) w[q] = wp[q];
            const float b = bv1[i];
            for (int r = 0; r < 4; ++r) {
                float acc = b;
                #pragma unroll
                for (int q = 0; q < 16; ++q) {
                    acc = fmaf(w[q].x, xs[r][q*4+0], acc);
                    acc = fmaf(w[q].y, xs[r][q*4+1], acc);
                    acc = fmaf(w[q].z, xs[r][q*4+2], acc);
                    acc = fmaf(w[q].w, xs[r][q*4+3], acc);
                }
                sA[r][i] = (acc >= 0.f) ? acc : 0.1f * acc;
            }
        }
        __syncthreads();

        // phase 2: h[r][i] = bv2[i] + h1[r] . Wv2[i, :]
        {
            float4 w[32];
            const float4* wp = reinterpret_cast<const float4*>(Wv2 + i * GHH);
            #pragma unroll
            for (int q = 0; q < 32; ++q) w[q] = wp[q];
            const float b = bv2[i];
            for (int r = 0; r < 4; ++r) {
                float acc = b;
                const float4* hp = reinterpret_cast<const float4*>(sA[r]);
                #pragma unroll
                for (int q = 0; q < 32; ++q) {
                    float4 h4 = hp[q];
                    acc = fmaf(w[q].x, h4.x, acc);
                    acc = fmaf(w[q].y, h4.y, acc);
                    acc = fmaf(w[q].z, h4.z, acc);
                    acc = fmaf(w[q].w, h4.w, acc);
                }
                sB[r][i] = acc;   // no activation on h
            }
        }
        __syncthreads();

        // phase 3: hr[r][i] = h[r] . Wm1[i, :128];  a[n] = 0.55 * sum w*hr
        {
            float4 w[32];
            const float4* wp = reinterpret_cast<const float4*>(Wm1 + i * 192);
            #pragma unroll
            for (int q = 0; q < 32; ++q) w[q] = wp[q];
            const float wm2 = Wm2[i];
            for (int r = 0; r < 4; ++r) {
                float acc = 0.f;
                const float4* hp = reinterpret_cast<const float4*>(sB[r]);
                #pragma unroll
                for (int q = 0; q < 32; ++q) {
                    float4 h4 = hp[q];
                    acc = fmaf(w[q].x, h4.x, acc);
                    acc = fmaf(w[q].y, h4.y, acc);
                    acc = fmaf(w[q].z, h4.z, acc);
                    acc = fmaf(w[q].w, h4.w, acc);
                }
                HR[(r0 + r) * GHH + i] = acc;
                sR[r][i] = wm2 * acc;
            }
        }
        __syncthreads();
        {
            const int r = i >> 5, c = i & 31;
            float s = sR[r][c] + sR[r][c+32] + sR[r][c+64] + sR[r][c+96];
            #pragma unroll
            for (int off = 16; off >= 1; off >>= 1) s += __shfl_xor(s, off, 32);
            if (c == 0) av[r0 + r] = 0.55f * s;
        }
    } else {
        // -------- task path --------
        const int t0 = (blockIdx.x - NRB / 4) * 4;
        ((float*)xs)[i]       = xt[t0 * DD + i];
        ((float*)xs)[128 + i] = xt[t0 * DD + 128 + i];
        __syncthreads();

        float4 w[16];
        const float4* wp = reinterpret_cast<const float4*>(Wm1 + i * 192 + 128);
        #pragma unroll
        for (int q = 0; q < 16; ++q) w[q] = wp[q];
        const float b   = bm1[i];
        const float wm2 = Wm2[i];
        for (int t = 0; t < 4; ++t) {
            float acc = b;
            #pragma unroll
            for (int q = 0; q < 16; ++q) {
                acc = fmaf(w[q].x, xs[t][q*4+0], acc);
                acc = fmaf(w[q].y, xs[t][q*4+1], acc);
                acc = fmaf(w[q].z, xs[t][q*4+2], acc);
                acc = fmaf(w[q].w, xs[t][q*4+3], acc);
            }
            HTB[(t0 + t) * GHH + i] = acc;   // includes bm1
            sR[t][i] = wm2 * acc;
        }
        __syncthreads();
        {
            const int r = i >> 5, c = i & 31;
            float s = sR[r][c] + sR[r][c+32] + sR[r][c+64] + sR[r][c+96];
            #pragma unroll
            for (int off = 16; off >= 1; off >>= 1) s += __shfl_xor(s, off, 32);
            if (c == 0) cv[t0 + r] = 0.55f * s + bm2[0];
        }
        if (blockIdx.x == NRB / 4 && i < GHH) wbv[i] = 0.45f * wm2;
    }
}

// ---------------------------------------------------------------------------
// Kernel B: fused score + softmax. 256 blocks x 1024 threads.
// Block b owns rows n0=2b, 2b+1; thread tid owns column m=tid (all 1024 m
// covered by the block). Per hc chunk of 32 h: thread loads its HTB chunk
// (8 float4, per-lane vmem) once and reuses it for both rows; HR and wb are
// block-uniform -> scalar loads. Then block-local softmax per row via wave
// shfl reduce + 16-wave LDS combine; coalesced store.
// ---------------------------------------------------------------------------
__global__ __launch_bounds__(1024) void score_softmax_kernel(
    const float* __restrict__ HR, const float* __restrict__ HTB,
    const float* __restrict__ av, const float* __restrict__ cv,
    const float* __restrict__ wbv, float* __restrict__ out)
{
    const int b   = blockIdx.x;     // 0..255
    const int tid = threadIdx.x;    // 0..1023 == m
    const int n0  = b * 2;

    float accA[2] = {0.f, 0.f}, accB[2] = {0.f, 0.f};
    const float4* htbp = reinterpret_cast<const float4*>(HTB + tid * GHH);

    #pragma unroll 1
    for (int hc = 0; hc < 4; ++hc) {
        float4 hb[8];
        #pragma unroll
        for (int q = 0; q < 8; ++q) hb[q] = htbp[hc * 8 + q];
        float4 wr[8];
        const float4* wp = reinterpret_cast<const float4*>(wbv + hc * 32);
        #pragma unroll
        for (int q = 0; q < 8; ++q) wr[q] = wp[q];

        #pragma unroll
        for (int n = 0; n < 2; ++n) {
            const float4* hrp =
                reinterpret_cast<const float4*>(HR + (n0 + n) * GHH + hc * 32);
            float a0 = 0.f, a1 = 0.f;
            #pragma unroll
            for (int q = 0; q < 8; ++q) {
                float4 h4 = hrp[q];
                float x0 = h4.x + hb[q].x;
                float x1 = h4.y + hb[q].y;
                float x2 = h4.z + hb[q].z;
                float x3 = h4.w + hb[q].w;
                a0 = fmaf(wr[q].x, fabsf(x0), a0);
                a1 = fmaf(wr[q].y, fabsf(x1), a1);
                a0 = fmaf(wr[q].z, fabsf(x2), a0);
                a1 = fmaf(wr[q].w, fabsf(x3), a1);
            }
            accA[n] += a0; accB[n] += a1;
        }
    }

    const float cm = cv[tid];
    float sc[2];
    #pragma unroll
    for (int n = 0; n < 2; ++n)
        sc[n] = accA[n] + accB[n] + av[n0 + n] + cm;

    // ---- block-local softmax over the 1024 columns, both rows ----
    __shared__ float rmax[2][16], rsum[2][16];
    const int wid = tid >> 6, lane = tid & 63;

    #pragma unroll
    for (int n = 0; n < 2; ++n) {
        float mx = sc[n];
        #pragma unroll
        for (int off = 32; off >= 1; off >>= 1)
            mx = fmaxf(mx, __shfl_xor(mx, off, 64));
        if (lane == 0) rmax[n][wid] = mx;
    }
    __syncthreads();

    float ex[2];
    #pragma unroll
    for (int n = 0; n < 2; ++n) {
        float mx = rmax[n][0];
        #pragma unroll
        for (int k = 1; k < 16; ++k) mx = fmaxf(mx, rmax[n][k]);
        float e = expf(sc[n] - mx);
        ex[n] = e;
        float s = e;
        #pragma unroll
        for (int off = 32; off >= 1; off >>= 1) s += __shfl_xor(s, off, 64);
        if (lane == 0) rsum[n][wid] = s;
    }
    __syncthreads();

    #pragma unroll
    for (int n = 0; n < 2; ++n) {
        float s = rsum[n][0];
        #pragma unroll
        for (int k = 1; k < 16; ++k) s += rsum[n][k];
        out[(n0 + n) * NTK + tid] = ex[n] * (1.0f / s);
    }
}

extern "C" void kernel_launch(void* const* d_in, const int* in_sizes, int n_in,
                              void* d_out, int out_size, void* d_ws, size_t ws_size,
                              hipStream_t stream)
{
    const float* xr  = (const float*)d_in[0];
    const float* xt  = (const float*)d_in[1];
    // d_in[2]=edge_index, [3]=edge_attr, [4..7]=We1,be1,We2,be2 : provably dead
    const float* Wv1 = (const float*)d_in[8];
    const float* bv1 = (const float*)d_in[9];
    const float* Wv2 = (const float*)d_in[10];
    const float* bv2 = (const float*)d_in[11];
    const float* Wm1 = (const float*)d_in[12];
    const float* bm1 = (const float*)d_in[13];
    const float* Wm2 = (const float*)d_in[14];
    const float* bm2 = (const float*)d_in[15];

    float* ws  = (float*)d_ws;
    float* HR  = ws;
    float* HTB = ws + 65536;
    float* av  = ws + 196608;
    float* cv  = ws + 197120;
    float* wbv = ws + 198144;
    float* out = (float*)d_out;

    hipLaunchKernelGGL(prep_kernel, dim3(384), dim3(128), 0, stream,
                       xr, xt, Wv1, bv1, Wv2, bv2, Wm1, bm1, Wm2, bm2,
                       HR, HTB, av, cv, wbv);
    hipLaunchKernelGGL(score_softmax_kernel, dim3(256), dim3(1024), 0, stream,
                       HR, HTB, av, cv, wbv, out);
}